// Round 14
// baseline (90.282 us; speedup 1.0000x reference)
//
#include <hip/hip_runtime.h>
#include <hip/hip_bf16.h>

// GQA paged-prefill attention, MI355X gfx950.
// Causal mask j<=i over concat(past,new) => only first Q_LEN (=1024) gathered
// past tokens are live. Flash-attention over tokens 0..1023 of paged cache.
//
// R14: 2-head fattened waves for qt>=8 (kv-split halves, combine), 1-head
// direct for qt<8. Every K/V ds_read + addr calc feeds BOTH GQA heads of a
// pair => fixed per-tile cost amortized 2x over 75% of the work. Grid 512,
// 80KB LDS -> 2 blocks/CU. Counted-vmcnt pipeline kept from R13.

#define Q_STRIDE 4096
#define SCALE 0.08838834764831845f
#define RESCALE_THR 8.0f
#define KSW_TILE 16384                     // bytes per (hkv, 64-tok tile)
#define VSW_OFF  (2 * 1024 * 1024)         // V^T tiles at +2MB
#define ACC1_OFF (4 * 1024 * 1024)         // half1 acc bf16: 16384 rows x 256B
#define ML0_OFF  (ACC1_OFF + 16384 * 256)  // half0 (m,l): 16384 x 8B
#define ML1_OFF  (ML0_OFF + 16384 * 8)     // half1 (m,l): 16384 x 8B

typedef short short8 __attribute__((ext_vector_type(8)));
typedef float f32x4 __attribute__((ext_vector_type(4)));
typedef unsigned short ushort_t;
typedef unsigned int uint_t;

__device__ __forceinline__ ushort_t f2bf(float f) {
    return __builtin_bit_cast(ushort_t, __float2bfloat16(f));
}
__device__ __forceinline__ uint_t pk2(float a, float b) {
    return (uint_t)f2bf(a) | ((uint_t)f2bf(b) << 16);
}
__device__ __forceinline__ float bf2f(ushort_t u) {
    uint_t x = ((uint_t)u) << 16;
    return __builtin_bit_cast(float, x);
}

// ---------------- prep: paged fp32 -> dense swizzled bf16 ----------------
__launch_bounds__(256)
__global__ void prep_kv(const float* __restrict__ kvc,
                        const int* __restrict__ bt,
                        char* __restrict__ wsb)
{
    __shared__ float sVt[64 * 128];
    const int blk = blockIdx.x;        // 128 blocks = hkv(8) x jb(16)
    const int hkv = blk >> 4;
    const int jb  = blk & 15;
    const int tid = threadIdx.x;
    char* kout = wsb + (size_t)(hkv * 16 + jb) * KSW_TILE;
    char* vout = wsb + VSW_OFF + (size_t)(hkv * 16 + jb) * KSW_TILE;

#pragma unroll
    for (int i = 0; i < 4; ++i) {
        const int u = tid + i * 256;   // t(64) x c(16)
        const int t = u >> 4, c = u & 15;
        const int gtok = jb * 64 + t;
        const int page = bt[gtok >> 4];
        const float* src = kvc + (size_t)page * 32768 + (size_t)hkv * 2048
                         + (gtok & 15) * 128 + c * 8;
        float4 a = *(const float4*)src;
        float4 b = *(const float4*)(src + 4);
        uint4 p;
        p.x = pk2(a.x, a.y); p.y = pk2(a.z, a.w);
        p.z = pk2(b.x, b.y); p.w = pk2(b.z, b.w);
        *(uint4*)(kout + t * 256 + ((c * 16) ^ ((t & 7) << 4))) = p;
    }
#pragma unroll
    for (int i = 0; i < 8; ++i) {
        const int u = tid + i * 256;   // t(64) x c4(32)
        const int t = u >> 5, c4 = u & 31;
        const int gtok = jb * 64 + t;
        const int page = bt[gtok >> 4];
        const float* src = kvc + (size_t)page * 32768 + 16384
                         + (size_t)hkv * 2048 + (gtok & 15) * 128 + c4 * 4;
        *(float4*)(sVt + t * 128 + c4 * 4) = *(const float4*)src;
    }
    __syncthreads();
#pragma unroll
    for (int i = 0; i < 4; ++i) {
        const int u = tid + i * 256;   // d(128) x ch(8)
        const int d = u >> 3, ch = u & 7;
        float v[8];
#pragma unroll
        for (int k = 0; k < 8; ++k) v[k] = sVt[(8 * ch + k) * 128 + d];
        uint4 p;
        p.x = pk2(v[0], v[1]); p.y = pk2(v[2], v[3]);
        p.z = pk2(v[4], v[5]); p.w = pk2(v[6], v[7]);
        *(uint4*)(vout + ((d * 128 + 16 * ch) ^ ((d & 7) << 4))) = p;
    }
}

// ---------------- main attention ----------------
#define GLL16(G, L) __builtin_amdgcn_global_load_lds(                         \
    (const uint_t __attribute__((address_space(1)))*)(G),                     \
    (uint_t __attribute__((address_space(3)))*)(L), 16, 0, 0)

#define STAGE(JB, KB, VB) {                                                   \
    const char* ks = kvbf + (size_t)(hkv * 16 + (JB)) * KSW_TILE              \
                   + w * 4096 + lane * 16;                                    \
    const char* vs = ks + VSW_OFF;                                            \
    _Pragma("unroll")                                                         \
    for (int i = 0; i < 4; ++i) {                                             \
        GLL16(ks + i * 1024, (KB) + w * 4096 + i * 1024);                     \
        GLL16(vs + i * 1024, (VB) + w * 4096 + i * 1024);                     \
    }                                                                         \
}

// softmax + P-store for one head (HD = A or B). Constant indices only.
#define SOFTMAX_P(SACC, MRUN, LPART, ACC, PB) {                               \
    if (diag) {                                                               \
        _Pragma("unroll")                                                     \
        for (int n = 0; n < 4; ++n)                                           \
            _Pragma("unroll")                                                 \
            for (int j = 0; j < 4; ++j) {                                     \
                const int tok = jb * 64 + n * 16 + l15;                       \
                const int qg  = qt * 64 + rg * 16 + lhi * 4 + j;              \
                if (tok > qg) SACC[n][j] = -1e30f;                            \
            }                                                                 \
    }                                                                         \
    _Pragma("unroll")                                                         \
    for (int j = 0; j < 4; ++j) {                                             \
        float lmax = fmaxf(fmaxf(SACC[0][j], SACC[1][j]),                     \
                           fmaxf(SACC[2][j], SACC[3][j]));                    \
        if (__any(lmax > MRUN[j] + RESCALE_THR)) {                            \
            float mt = lmax;                                                  \
            _Pragma("unroll")                                                 \
            for (int off = 1; off < 16; off <<= 1)                            \
                mt = fmaxf(mt, __shfl_xor(mt, off));                          \
            const float mn = fmaxf(MRUN[j], mt);                              \
            const float alpha = __expf(MRUN[j] - mn);                         \
            MRUN[j] = mn;                                                     \
            LPART[j] *= alpha;                                                \
            _Pragma("unroll")                                                 \
            for (int n2 = 0; n2 < 8; ++n2) ACC[n2][j] *= alpha;               \
        }                                                                     \
        float ls = 0.f;                                                       \
        _Pragma("unroll")                                                     \
        for (int n = 0; n < 4; ++n) {                                         \
            float p = __expf(SACC[n][j] - MRUN[j]);                           \
            SACC[n][j] = p;                                                   \
            ls += p;                                                          \
        }                                                                     \
        LPART[j] += ls;                                                       \
    }                                                                         \
    _Pragma("unroll")                                                         \
    for (int n = 0; n < 4; ++n)                                               \
        _Pragma("unroll")                                                     \
        for (int j = 0; j < 4; ++j) {                                         \
            const int r = lhi * 4 + j;                                        \
            const uint_t byte = (uint_t)(r * 128)                             \
                + (((uint_t)((n * 16 + l15) * 2)) ^ ((uint_t)((r & 7) << 4)));\
            *(ushort_t*)((PB) + byte) = f2bf(SACC[n][j]);                     \
        }                                                                     \
}

__launch_bounds__(256)
__global__ void attn_main(const float* __restrict__ q,
                          const char* __restrict__ kvbf,
                          float* __restrict__ out,
                          char* __restrict__ wsb)
{
    __shared__ __align__(16) char sK[2][16384];
    __shared__ __align__(16) char sV[2][16384];
    __shared__ __align__(16) char sP[4][2][2048];

    const int bid = blockIdx.x;
    // bid<256: SPLIT (qt>=8, 2-head waves, kv halves). bid>=256: DIRECT
    // (qt<8, 1-head, full range).
    int qt, jb0, jb1, h0, hkv, mode;   // mode 0 direct, 1 half0, 2 half1
    bool two;
    if (bid < 256) {
        const int half = bid & 1;
        const int idx  = bid >> 1;     // 0..127 = g(8) x hp(16)
        qt  = 15 - (idx >> 4);         // 15..8
        const int hp = idx & 15;
        h0  = hp * 2;
        hkv = hp >> 1;
        const int nt  = qt + 1;
        const int nt0 = (nt + 1) >> 1;
        jb0 = half ? nt0 : 0;
        jb1 = half ? nt : nt0;
        mode = half ? 2 : 1;
        two = true;
    } else {
        const int didx = bid - 256;
        qt  = 7 - (didx >> 5);         // 7..0 (long first)
        h0  = didx & 31;
        hkv = h0 >> 2;
        jb0 = 0; jb1 = qt + 1;
        mode = 0;
        two = false;
    }
    const int tid  = threadIdx.x;
    const int w    = tid >> 6;
    const int lane = tid & 63;
    const int l15  = lane & 15;
    const int lhi  = lane >> 4;
    const int rg   = w;                // 16-row group

    // ---- Q fragments (SCALE folded)
    short8 qfA[4], qfB[4];
    {
        const int qrow = qt * 64 + rg * 16 + l15;
        const float* qp = q + (size_t)qrow * Q_STRIDE + h0 * 128;
#pragma unroll
        for (int s = 0; s < 4; ++s) {
            const int d0 = s * 32 + lhi * 8;
            float4 a = *(const float4*)(qp + d0);
            float4 b = *(const float4*)(qp + d0 + 4);
            short8 v;
            v[0] = (short)f2bf(a.x * SCALE); v[1] = (short)f2bf(a.y * SCALE);
            v[2] = (short)f2bf(a.z * SCALE); v[3] = (short)f2bf(a.w * SCALE);
            v[4] = (short)f2bf(b.x * SCALE); v[5] = (short)f2bf(b.y * SCALE);
            v[6] = (short)f2bf(b.z * SCALE); v[7] = (short)f2bf(b.w * SCALE);
            qfA[s] = v;
            if (two) {
                float4 a2 = *(const float4*)(qp + 128 + d0);
                float4 b2 = *(const float4*)(qp + 128 + d0 + 4);
                short8 v2;
                v2[0] = (short)f2bf(a2.x * SCALE); v2[1] = (short)f2bf(a2.y * SCALE);
                v2[2] = (short)f2bf(a2.z * SCALE); v2[3] = (short)f2bf(a2.w * SCALE);
                v2[4] = (short)f2bf(b2.x * SCALE); v2[5] = (short)f2bf(b2.y * SCALE);
                v2[6] = (short)f2bf(b2.z * SCALE); v2[7] = (short)f2bf(b2.w * SCALE);
                qfB[s] = v2;
            }
        }
    }

    f32x4 accA[8], accB[8];
#pragma unroll
    for (int n2 = 0; n2 < 8; ++n2) {
        accA[n2] = (f32x4){0.f, 0.f, 0.f, 0.f};
        accB[n2] = (f32x4){0.f, 0.f, 0.f, 0.f};
    }
    float mA[4] = {-1e30f, -1e30f, -1e30f, -1e30f};
    float lA[4] = {0.f, 0.f, 0.f, 0.f};
    float mB[4] = {-1e30f, -1e30f, -1e30f, -1e30f};
    float lB[4] = {0.f, 0.f, 0.f, 0.f};

    STAGE(jb0, sK[0], sV[0])
    __syncthreads();

    for (int jb = jb0; jb < jb1; ++jb) {
        const int cur = (jb - jb0) & 1;
        char* kbuf = sK[cur];
        char* vbuf = sV[cur];
        const bool pf = (jb + 1 < jb1);
        if (pf) {
            STAGE(jb + 1, sK[cur ^ 1], sV[cur ^ 1])
            asm volatile("s_waitcnt vmcnt(8)" ::: "memory");
        } else {
            asm volatile("s_waitcnt vmcnt(0)" ::: "memory");
        }
        __builtin_amdgcn_sched_barrier(0);
        __builtin_amdgcn_s_barrier();
        __builtin_amdgcn_sched_barrier(0);

        // ---- S = Q K^T : each kb read feeds BOTH heads
        f32x4 saccA[4], saccB[4];
#pragma unroll
        for (int n = 0; n < 4; ++n) {
            saccA[n] = (f32x4){0.f, 0.f, 0.f, 0.f};
            saccB[n] = (f32x4){0.f, 0.f, 0.f, 0.f};
        }
#pragma unroll
        for (int s = 0; s < 4; ++s) {
#pragma unroll
            for (int n = 0; n < 4; ++n) {
                const int tok = n * 16 + l15;
                const uint_t byte = (uint_t)(tok * 256)
                    + (((uint_t)((s * 32 + lhi * 8) * 2)) ^ ((uint_t)((tok & 7) << 4)));
                short8 kb = *(const short8*)(kbuf + byte);
                saccA[n] = __builtin_amdgcn_mfma_f32_16x16x32_bf16(qfA[s], kb, saccA[n], 0, 0, 0);
                if (two)
                    saccB[n] = __builtin_amdgcn_mfma_f32_16x16x32_bf16(qfB[s], kb, saccB[n], 0, 0, 0);
            }
        }

        const bool diag = (jb == qt);
        SOFTMAX_P(saccA, mA, lA, accA, sP[w][0])
        if (two) {
            SOFTMAX_P(saccB, mB, lB, accB, sP[w][1])
        }

        // ---- O += P V : each vb read feeds BOTH heads
#pragma unroll
        for (int s2 = 0; s2 < 2; ++s2) {
            const uint_t pbyte = (uint_t)(l15 * 128)
                + (((uint_t)((s2 * 32 + lhi * 8) * 2)) ^ ((uint_t)((l15 & 7) << 4)));
            short8 paA = *(const short8*)(sP[w][0] + pbyte);
            short8 paB = *(const short8*)(sP[w][1] + pbyte);
#pragma unroll
            for (int n2 = 0; n2 < 8; ++n2) {
                const int dim = n2 * 16 + l15;
                const uint_t vbyte = (uint_t)(dim * 128)
                    + (((uint_t)((s2 * 32 + lhi * 8) * 2)) ^ ((uint_t)((dim & 7) << 4)));
                short8 vbf = *(const short8*)(vbuf + vbyte);
                accA[n2] = __builtin_amdgcn_mfma_f32_16x16x32_bf16(paA, vbf, accA[n2], 0, 0, 0);
                if (two)
                    accB[n2] = __builtin_amdgcn_mfma_f32_16x16x32_bf16(paB, vbf, accB[n2], 0, 0, 0);
            }
        }

        if (pf) {
            __builtin_amdgcn_sched_barrier(0);
            __builtin_amdgcn_s_barrier();
        }
    }

    // ---- epilogue
#pragma unroll
    for (int j = 0; j < 4; ++j) {
        float lsA = lA[j];
        float lsB = lB[j];
#pragma unroll
        for (int off = 1; off < 16; off <<= 1) {
            lsA += __shfl_xor(lsA, off);
            lsB += __shfl_xor(lsB, off);
        }
        const int row64 = rg * 16 + lhi * 4 + j;
        const int qg    = qt * 64 + row64;
        if (mode == 0) {
            const float inv = 1.0f / lsA;
            float* dst = out + (size_t)qg * Q_STRIDE + h0 * 128;
#pragma unroll
            for (int n2 = 0; n2 < 8; ++n2)
                dst[n2 * 16 + l15] = accA[n2][j] * inv;
        } else if (mode == 1) {
            float* dA = out + (size_t)qg * Q_STRIDE + h0 * 128;
            float* dB = dA + 128;
#pragma unroll
            for (int n2 = 0; n2 < 8; ++n2) {
                dA[n2 * 16 + l15] = accA[n2][j];
                dB[n2 * 16 + l15] = accB[n2][j];
            }
            if (l15 == 0) {
                const int ia = h0 * 512 + (qt - 8) * 64 + row64;
                float* ml = (float*)(wsb + ML0_OFF);
                ml[(size_t)ia * 2]           = mA[j];
                ml[(size_t)ia * 2 + 1]       = lsA;
                ml[(size_t)(ia + 512) * 2]     = mB[j];
                ml[(size_t)(ia + 512) * 2 + 1] = lsB;
            }
        } else {
            ushort_t* ab = (ushort_t*)(wsb + ACC1_OFF);
            const int ia = h0 * 512 + (qt - 8) * 64 + row64;
#pragma unroll
            for (int n2 = 0; n2 < 8; ++n2) {
                ab[(size_t)ia * 128 + n2 * 16 + l15]         = f2bf(accA[n2][j]);
                ab[(size_t)(ia + 512) * 128 + n2 * 16 + l15] = f2bf(accB[n2][j]);
            }
            if (l15 == 0) {
                float* ml = (float*)(wsb + ML1_OFF);
                ml[(size_t)ia * 2]           = mA[j];
                ml[(size_t)ia * 2 + 1]       = lsA;
                ml[(size_t)(ia + 512) * 2]     = mB[j];
                ml[(size_t)(ia + 512) * 2 + 1] = lsB;
            }
        }
    }
}

// ---------------- combine (qt>=8 rows only) ----------------
__launch_bounds__(256)
__global__ void attn_combine(float* __restrict__ out, const char* __restrict__ wsb)
{
    const int pid = blockIdx.x;           // 256 = (qt-8)(8) x h(32)
    const int qt = 8 + (pid >> 5);
    const int h  = pid & 31;
    const int tid = threadIdx.x;
    const int d4  = (tid & 31) * 4;
    const float* ml0b = (const float*)(wsb + ML0_OFF);
    const float* ml1b = (const float*)(wsb + ML1_OFF);
    const ushort_t* a1b = (const ushort_t*)(wsb + ACC1_OFF);

#pragma unroll
    for (int p = 0; p < 8; ++p) {
        const int r = (tid >> 5) + p * 8;            // row 0..63
        const size_t idx = (size_t)h * 512 + (qt - 8) * 64 + r;
        const float m1 = ml0b[idx * 2], l1 = ml0b[idx * 2 + 1];
        const float m2 = ml1b[idx * 2], l2 = ml1b[idx * 2 + 1];
        const float m  = fmaxf(m1, m2);
        const float a1 = __expf(m1 - m), a2 = __expf(m2 - m);
        const float inv = 1.0f / (l1 * a1 + l2 * a2);
        float* o = out + (size_t)(qt * 64 + r) * Q_STRIDE + h * 128 + d4;
        const ushort_t* y4 = a1b + idx * 128 + d4;
        float4 x = *(const float4*)o;
        x.x = (x.x * a1 + bf2f(y4[0]) * a2) * inv;
        x.y = (x.y * a1 + bf2f(y4[1]) * a2) * inv;
        x.z = (x.z * a1 + bf2f(y4[2]) * a2) * inv;
        x.w = (x.w * a1 + bf2f(y4[3]) * a2) * inv;
        *(float4*)o = x;
    }
}

extern "C" void kernel_launch(void* const* d_in, const int* in_sizes, int n_in,
                              void* d_out, int out_size, void* d_ws, size_t ws_size,
                              hipStream_t stream) {
    const float* q   = (const float*)d_in[0];
    // d_in[1] (k) and d_in[2] (v) are dead under the reference's causal mask.
    const float* kvc = (const float*)d_in[3];
    const int*   bt  = (const int*)d_in[4];
    float* out = (float*)d_out;
    char*  wsb = (char*)d_ws;
    prep_kv<<<dim3(128), dim3(256), 0, stream>>>(kvc, bt, wsb);
    attn_main<<<dim3(512), dim3(256), 0, stream>>>(q, wsb, out, wsb);
    attn_combine<<<dim3(256), dim3(256), 0, stream>>>(out, wsb);
}

// Round 15
// 86.760 us; speedup vs baseline: 1.0406x; 1.0406x over previous
//
#include <hip/hip_runtime.h>
#include <hip/hip_bf16.h>

// GQA paged-prefill attention, MI355X gfx950.
// Causal mask j<=i over concat(past,new) => only first Q_LEN (=1024) gathered
// past tokens are live. Flash-attention over tokens 0..1023 of paged cache.
//
// R15: V^T read DIRECT from L2-resident ws into registers (issued under
// softmax); only K staged in LDS (dbuf). LDS 40KB -> 3 blocks/CU (grid 768:
// qt>=8 kv-split halves + combine, qt<8 direct) -> 3 streams/SIMD at
// unchanged chain count/length. __launch_bounds__(256,4) caps VGPR <= 128.

#define Q_STRIDE 4096
#define SCALE 0.08838834764831845f
#define RESCALE_THR 8.0f
#define KSW_TILE 16384                     // bytes per (hkv, 64-tok tile)
#define VSW_OFF  (2 * 1024 * 1024)         // linear V^T tiles at +2MB
#define ACC1_OFF (4 * 1024 * 1024)         // half1 acc bf16: 32768 rows x 256B
#define ML0_OFF  (ACC1_OFF + 32768 * 256)  // half0 (m,l): 32768 x 8B
#define ML1_OFF  (ML0_OFF + 32768 * 8)     // half1 (m,l): 32768 x 8B

typedef short short8 __attribute__((ext_vector_type(8)));
typedef float f32x4 __attribute__((ext_vector_type(4)));
typedef unsigned short ushort_t;
typedef unsigned int uint_t;

__device__ __forceinline__ ushort_t f2bf(float f) {
    return __builtin_bit_cast(ushort_t, __float2bfloat16(f));
}
__device__ __forceinline__ uint_t pk2(float a, float b) {
    return (uint_t)f2bf(a) | ((uint_t)f2bf(b) << 16);
}
__device__ __forceinline__ float bf2f(ushort_t u) {
    uint_t x = ((uint_t)u) << 16;
    return __builtin_bit_cast(float, x);
}

// ---------------- prep: paged fp32 -> dense bf16 (K swizzled, V^T linear) --
__launch_bounds__(256)
__global__ void prep_kv(const float* __restrict__ kvc,
                        const int* __restrict__ bt,
                        char* __restrict__ wsb)
{
    __shared__ float sVt[64 * 128];
    const int blk = blockIdx.x;        // 128 blocks = hkv(8) x jb(16)
    const int hkv = blk >> 4;
    const int jb  = blk & 15;
    const int tid = threadIdx.x;
    char* kout = wsb + (size_t)(hkv * 16 + jb) * KSW_TILE;
    char* vout = wsb + VSW_OFF + (size_t)(hkv * 16 + jb) * KSW_TILE;

    // K: [t 64][d 128] bf16, 16B chunk c at byte t*256 + ((c*16)^((t&7)<<4))
#pragma unroll
    for (int i = 0; i < 4; ++i) {
        const int u = tid + i * 256;   // t(64) x c(16)
        const int t = u >> 4, c = u & 15;
        const int gtok = jb * 64 + t;
        const int page = bt[gtok >> 4];
        const float* src = kvc + (size_t)page * 32768 + (size_t)hkv * 2048
                         + (gtok & 15) * 128 + c * 8;
        float4 a = *(const float4*)src;
        float4 b = *(const float4*)(src + 4);
        uint4 p;
        p.x = pk2(a.x, a.y); p.y = pk2(a.z, a.w);
        p.z = pk2(b.x, b.y); p.w = pk2(b.z, b.w);
        *(uint4*)(kout + t * 256 + ((c * 16) ^ ((t & 7) << 4))) = p;
    }
    // V: coalesced fp32 read -> LDS ([t][d])
#pragma unroll
    for (int i = 0; i < 8; ++i) {
        const int u = tid + i * 256;   // t(64) x c4(32)
        const int t = u >> 5, c4 = u & 31;
        const int gtok = jb * 64 + t;
        const int page = bt[gtok >> 4];
        const float* src = kvc + (size_t)page * 32768 + 16384
                         + (size_t)hkv * 2048 + (gtok & 15) * 128 + c4 * 4;
        *(float4*)(sVt + t * 128 + c4 * 4) = *(const float4*)src;
    }
    __syncthreads();
    // V^T: [d 128][t 64] bf16 LINEAR (read direct to regs in main; no banks)
#pragma unroll
    for (int i = 0; i < 4; ++i) {
        const int u = tid + i * 256;   // d(128) x ch(8)
        const int d = u >> 3, ch = u & 7;
        float v[8];
#pragma unroll
        for (int k = 0; k < 8; ++k) v[k] = sVt[(8 * ch + k) * 128 + d];
        uint4 p;
        p.x = pk2(v[0], v[1]); p.y = pk2(v[2], v[3]);
        p.z = pk2(v[4], v[5]); p.w = pk2(v[6], v[7]);
        *(uint4*)(vout + d * 128 + 16 * ch) = p;
    }
}

// ---------------- main attention ----------------
#define GLL16(G, L) __builtin_amdgcn_global_load_lds(                         \
    (const uint_t __attribute__((address_space(1)))*)(G),                     \
    (uint_t __attribute__((address_space(3)))*)(L), 16, 0, 0)

// Stage K tile JB only: 4 glls/thread (16KB).
#define STAGE_K(JB, KB) {                                                     \
    const char* ks = kvbf + (size_t)(hkv * 16 + (JB)) * KSW_TILE              \
                   + w * 4096 + lane * 16;                                    \
    _Pragma("unroll")                                                         \
    for (int i = 0; i < 4; ++i)                                               \
        GLL16(ks + i * 1024, (KB) + w * 4096 + i * 1024);                     \
}

__launch_bounds__(256, 4)
__global__ void attn_main(const float* __restrict__ q,
                          const char* __restrict__ kvbf,
                          float* __restrict__ out,
                          char* __restrict__ wsb)
{
    __shared__ __align__(16) char sK[2][16384];
    __shared__ __align__(16) char sP[4][2048];

    const int bid = blockIdx.x;
    // bid<512: SPLIT halves of qt>=8 (long first). bid>=512: DIRECT qt<8.
    int qt, jb0, jb1, h, mode;         // mode 0 direct, 1 half0, 2 half1
    if (bid < 512) {
        const int half = bid & 1;
        const int idx  = bid >> 1;     // 0..255 carries (qt, h)
        qt  = 15 - (idx >> 5);         // 15..8
        h   = idx & 31;
        const int nt  = qt + 1;
        const int nt0 = (nt + 1) >> 1;
        jb0 = half ? nt0 : 0;
        jb1 = half ? nt : nt0;
        mode = half ? 2 : 1;
    } else {
        const int didx = bid - 512;
        qt  = 7 - (didx >> 5);         // 7..0 (long first)
        h   = didx & 31;
        jb0 = 0; jb1 = qt + 1;
        mode = 0;
    }
    const int hkv = h >> 2;
    const int tid  = threadIdx.x;
    const int w    = tid >> 6;
    const int lane = tid & 63;
    const int l15  = lane & 15;
    const int lhi  = lane >> 4;
    const int rg   = w;                // 16-row group

    // ---- Q fragments (SCALE folded): wave rows qt*64 + rg*16 + l15
    short8 qf[4];
    {
        const int qrow = qt * 64 + rg * 16 + l15;
        const float* qp = q + (size_t)qrow * Q_STRIDE + h * 128;
#pragma unroll
        for (int s = 0; s < 4; ++s) {
            const int d0 = s * 32 + lhi * 8;
            float4 a = *(const float4*)(qp + d0);
            float4 b = *(const float4*)(qp + d0 + 4);
            short8 v;
            v[0] = (short)f2bf(a.x * SCALE); v[1] = (short)f2bf(a.y * SCALE);
            v[2] = (short)f2bf(a.z * SCALE); v[3] = (short)f2bf(a.w * SCALE);
            v[4] = (short)f2bf(b.x * SCALE); v[5] = (short)f2bf(b.y * SCALE);
            v[6] = (short)f2bf(b.z * SCALE); v[7] = (short)f2bf(b.w * SCALE);
            qf[s] = v;
        }
    }

    f32x4 acc[8];
#pragma unroll
    for (int n2 = 0; n2 < 8; ++n2) acc[n2] = (f32x4){0.f, 0.f, 0.f, 0.f};
    float m_run[4]  = {-1e30f, -1e30f, -1e30f, -1e30f};
    float l_part[4] = {0.f, 0.f, 0.f, 0.f};

    STAGE_K(jb0, sK[0])
    __syncthreads();

    char* pb = sP[w];
    for (int jb = jb0; jb < jb1; ++jb) {
        const int cur = (jb - jb0) & 1;
        char* kbuf = sK[cur];
        const bool pf = (jb + 1 < jb1);
        if (pf) {
            STAGE_K(jb + 1, sK[cur ^ 1])
        }

        // ---- S = Q K^T
        f32x4 sacc[4];
#pragma unroll
        for (int n = 0; n < 4; ++n) sacc[n] = (f32x4){0.f, 0.f, 0.f, 0.f};
#pragma unroll
        for (int s = 0; s < 4; ++s) {
#pragma unroll
            for (int n = 0; n < 4; ++n) {
                const int tok = n * 16 + l15;
                const uint_t byte = (uint_t)(tok * 256)
                    + (((uint_t)((s * 32 + lhi * 8) * 2)) ^ ((uint_t)((tok & 7) << 4)));
                short8 kb = *(const short8*)(kbuf + byte);
                sacc[n] = __builtin_amdgcn_mfma_f32_16x16x32_bf16(qf[s], kb, sacc[n], 0, 0, 0);
            }
        }

        // ---- V^T fragments (s2=0) direct from L2; land during softmax
        const char* vt = kvbf + VSW_OFF + (size_t)(hkv * 16 + jb) * KSW_TILE;
        short8 vb0[8];
#pragma unroll
        for (int n2 = 0; n2 < 8; ++n2)
            vb0[n2] = *(const short8*)(vt + (n2 * 16 + l15) * 128 + lhi * 16);

        // ---- softmax with deferred max, in place
        const bool diag = (jb == qt);
        if (diag) {
#pragma unroll
            for (int n = 0; n < 4; ++n)
#pragma unroll
                for (int j = 0; j < 4; ++j) {
                    const int tok = jb * 64 + n * 16 + l15;
                    const int qg  = qt * 64 + rg * 16 + lhi * 4 + j;
                    if (tok > qg) sacc[n][j] = -1e30f;
                }
        }
#pragma unroll
        for (int j = 0; j < 4; ++j) {
            float lmax = fmaxf(fmaxf(sacc[0][j], sacc[1][j]),
                               fmaxf(sacc[2][j], sacc[3][j]));
            if (__any(lmax > m_run[j] + RESCALE_THR)) {
                float mt = lmax;
#pragma unroll
                for (int off = 1; off < 16; off <<= 1)
                    mt = fmaxf(mt, __shfl_xor(mt, off));
                const float mn = fmaxf(m_run[j], mt);
                const float alpha = __expf(m_run[j] - mn);
                m_run[j] = mn;
                l_part[j] *= alpha;
#pragma unroll
                for (int n2 = 0; n2 < 8; ++n2) acc[n2][j] *= alpha;
            }
            float ls = 0.f;
#pragma unroll
            for (int n = 0; n < 4; ++n) {
                float p = __expf(sacc[n][j] - m_run[j]);
                sacc[n][j] = p;
                ls += p;
            }
            l_part[j] += ls;
        }

        // ---- V^T fragments (s2=1); land during P write + PV pass 0
        short8 vb1[8];
#pragma unroll
        for (int n2 = 0; n2 < 8; ++n2)
            vb1[n2] = *(const short8*)(vt + (n2 * 16 + l15) * 128 + 64 + lhi * 16);

        // ---- P -> per-wave LDS (A-fragment relayout); same-wave lgkmcnt
#pragma unroll
        for (int n = 0; n < 4; ++n)
#pragma unroll
            for (int j = 0; j < 4; ++j) {
                const int r = lhi * 4 + j;
                const uint_t byte = (uint_t)(r * 128)
                    + (((uint_t)((n * 16 + l15) * 2)) ^ ((uint_t)((r & 7) << 4)));
                *(ushort_t*)(pb + byte) = f2bf(sacc[n][j]);
            }

        // ---- O += P V (V from registers)
        {
            const uint_t pbyte0 = (uint_t)(l15 * 128)
                + (((uint_t)((lhi * 8) * 2)) ^ ((uint_t)((l15 & 7) << 4)));
            short8 pa0 = *(const short8*)(pb + pbyte0);
#pragma unroll
            for (int n2 = 0; n2 < 8; ++n2)
                acc[n2] = __builtin_amdgcn_mfma_f32_16x16x32_bf16(pa0, vb0[n2], acc[n2], 0, 0, 0);
            const uint_t pbyte1 = (uint_t)(l15 * 128)
                + (((uint_t)((32 + lhi * 8) * 2)) ^ ((uint_t)((l15 & 7) << 4)));
            short8 pa1 = *(const short8*)(pb + pbyte1);
#pragma unroll
            for (int n2 = 0; n2 < 8; ++n2)
                acc[n2] = __builtin_amdgcn_mfma_f32_16x16x32_bf16(pa1, vb1[n2], acc[n2], 0, 0, 0);
        }

        if (pf) __syncthreads();   // drains K gll + guards buffer overwrite
    }

    // ---- epilogue
#pragma unroll
    for (int j = 0; j < 4; ++j) {
        float lsum = l_part[j];
#pragma unroll
        for (int off = 1; off < 16; off <<= 1)
            lsum += __shfl_xor(lsum, off);
        const int row64 = rg * 16 + lhi * 4 + j;
        const int qg    = qt * 64 + row64;
        if (mode == 0) {
            const float inv = 1.0f / lsum;
            float* dst = out + (size_t)qg * Q_STRIDE + h * 128;
#pragma unroll
            for (int n2 = 0; n2 < 8; ++n2)
                dst[n2 * 16 + l15] = acc[n2][j] * inv;
        } else {
            const int idx = (qt * 32 + h) * 64 + row64;
            if (mode == 1) {
                float* dst = out + (size_t)qg * Q_STRIDE + h * 128;
#pragma unroll
                for (int n2 = 0; n2 < 8; ++n2)
                    dst[n2 * 16 + l15] = acc[n2][j];   // unnormalized
                if (l15 == 0) {
                    float* ml = (float*)(wsb + ML0_OFF) + (size_t)idx * 2;
                    ml[0] = m_run[j]; ml[1] = lsum;
                }
            } else {
                ushort_t* dst = (ushort_t*)(wsb + ACC1_OFF) + (size_t)idx * 128;
#pragma unroll
                for (int n2 = 0; n2 < 8; ++n2)
                    dst[n2 * 16 + l15] = f2bf(acc[n2][j]);
                if (l15 == 0) {
                    float* ml = (float*)(wsb + ML1_OFF) + (size_t)idx * 2;
                    ml[0] = m_run[j]; ml[1] = lsum;
                }
            }
        }
    }
}

// ---------------- combine (qt>=8 rows only) ----------------
__launch_bounds__(256)
__global__ void attn_combine(float* __restrict__ out, const char* __restrict__ wsb)
{
    const int pid = blockIdx.x;           // 256 = (qt-8)(8) x h(32)
    const int qt = 8 + (pid >> 5);
    const int h  = pid & 31;
    const int tid = threadIdx.x;
    const int d4  = (tid & 31) * 4;
    const float* ml0b = (const float*)(wsb + ML0_OFF);
    const float* ml1b = (const float*)(wsb + ML1_OFF);
    const ushort_t* a1b = (const ushort_t*)(wsb + ACC1_OFF);

#pragma unroll
    for (int p = 0; p < 8; ++p) {
        const int r = (tid >> 5) + p * 8;            // row 0..63
        const size_t idx = (size_t)(qt * 32 + h) * 64 + r;
        const float m1 = ml0b[idx * 2], l1 = ml0b[idx * 2 + 1];
        const float m2 = ml1b[idx * 2], l2 = ml1b[idx * 2 + 1];
        const float m  = fmaxf(m1, m2);
        const float a1 = __expf(m1 - m), a2 = __expf(m2 - m);
        const float inv = 1.0f / (l1 * a1 + l2 * a2);
        float* o = out + (size_t)(qt * 64 + r) * Q_STRIDE + h * 128 + d4;
        const ushort_t* y4 = a1b + idx * 128 + d4;
        float4 x = *(const float4*)o;
        x.x = (x.x * a1 + bf2f(y4[0]) * a2) * inv;
        x.y = (x.y * a1 + bf2f(y4[1]) * a2) * inv;
        x.z = (x.z * a1 + bf2f(y4[2]) * a2) * inv;
        x.w = (x.w * a1 + bf2f(y4[3]) * a2) * inv;
        *(float4*)o = x;
    }
}

extern "C" void kernel_launch(void* const* d_in, const int* in_sizes, int n_in,
                              void* d_out, int out_size, void* d_ws, size_t ws_size,
                              hipStream_t stream) {
    const float* q   = (const float*)d_in[0];
    // d_in[1] (k) and d_in[2] (v) are dead under the reference's causal mask.
    const float* kvc = (const float*)d_in[3];
    const int*   bt  = (const int*)d_in[4];
    float* out = (float*)d_out;
    char*  wsb = (char*)d_ws;
    prep_kv<<<dim3(128), dim3(256), 0, stream>>>(kvc, bt, wsb);
    attn_main<<<dim3(768), dim3(256), 0, stream>>>(q, wsb, out, wsb);
    attn_combine<<<dim3(256), dim3(256), 0, stream>>>(out, wsb);
}

// Round 16
// 65.625 us; speedup vs baseline: 1.3757x; 1.3220x over previous
//
#include <hip/hip_runtime.h>
#include <hip/hip_bf16.h>

// GQA paged-prefill attention, MI355X gfx950.
// Causal mask j<=i over concat(past,new) => only first Q_LEN (=1024) gathered
// past tokens are live. Flash-attention over tokens 0..1023 of paged cache.
//
// R16 = R15 with the launch-bounds bug fixed: __launch_bounds__(256, 3)
// (min 3 waves/EU -> VGPR cap 170, no spill). R15's (256,4) forced VGPR=64
// and spilled the V-register fragments to scratch (FETCH/WRITE ~45MB).
// Structure: V^T direct from L2 ws into regs (under softmax); K staged in
// LDS dbuf; LDS 40KB; qt>=8 kv-split halves + combine, qt<8 direct.

#define Q_STRIDE 4096
#define SCALE 0.08838834764831845f
#define RESCALE_THR 8.0f
#define KSW_TILE 16384                     // bytes per (hkv, 64-tok tile)
#define VSW_OFF  (2 * 1024 * 1024)         // linear V^T tiles at +2MB
#define ACC1_OFF (4 * 1024 * 1024)         // half1 acc bf16: 32768 rows x 256B
#define ML0_OFF  (ACC1_OFF + 32768 * 256)  // half0 (m,l): 32768 x 8B
#define ML1_OFF  (ML0_OFF + 32768 * 8)     // half1 (m,l): 32768 x 8B

typedef short short8 __attribute__((ext_vector_type(8)));
typedef float f32x4 __attribute__((ext_vector_type(4)));
typedef unsigned short ushort_t;
typedef unsigned int uint_t;

__device__ __forceinline__ ushort_t f2bf(float f) {
    return __builtin_bit_cast(ushort_t, __float2bfloat16(f));
}
__device__ __forceinline__ uint_t pk2(float a, float b) {
    return (uint_t)f2bf(a) | ((uint_t)f2bf(b) << 16);
}
__device__ __forceinline__ float bf2f(ushort_t u) {
    uint_t x = ((uint_t)u) << 16;
    return __builtin_bit_cast(float, x);
}

// ---------------- prep: paged fp32 -> dense bf16 (K swizzled, V^T linear) --
__launch_bounds__(256)
__global__ void prep_kv(const float* __restrict__ kvc,
                        const int* __restrict__ bt,
                        char* __restrict__ wsb)
{
    __shared__ float sVt[64 * 128];
    const int blk = blockIdx.x;        // 128 blocks = hkv(8) x jb(16)
    const int hkv = blk >> 4;
    const int jb  = blk & 15;
    const int tid = threadIdx.x;
    char* kout = wsb + (size_t)(hkv * 16 + jb) * KSW_TILE;
    char* vout = wsb + VSW_OFF + (size_t)(hkv * 16 + jb) * KSW_TILE;

    // K: [t 64][d 128] bf16, 16B chunk c at byte t*256 + ((c*16)^((t&7)<<4))
#pragma unroll
    for (int i = 0; i < 4; ++i) {
        const int u = tid + i * 256;   // t(64) x c(16)
        const int t = u >> 4, c = u & 15;
        const int gtok = jb * 64 + t;
        const int page = bt[gtok >> 4];
        const float* src = kvc + (size_t)page * 32768 + (size_t)hkv * 2048
                         + (gtok & 15) * 128 + c * 8;
        float4 a = *(const float4*)src;
        float4 b = *(const float4*)(src + 4);
        uint4 p;
        p.x = pk2(a.x, a.y); p.y = pk2(a.z, a.w);
        p.z = pk2(b.x, b.y); p.w = pk2(b.z, b.w);
        *(uint4*)(kout + t * 256 + ((c * 16) ^ ((t & 7) << 4))) = p;
    }
    // V: coalesced fp32 read -> LDS ([t][d])
#pragma unroll
    for (int i = 0; i < 8; ++i) {
        const int u = tid + i * 256;   // t(64) x c4(32)
        const int t = u >> 5, c4 = u & 31;
        const int gtok = jb * 64 + t;
        const int page = bt[gtok >> 4];
        const float* src = kvc + (size_t)page * 32768 + 16384
                         + (size_t)hkv * 2048 + (gtok & 15) * 128 + c4 * 4;
        *(float4*)(sVt + t * 128 + c4 * 4) = *(const float4*)src;
    }
    __syncthreads();
    // V^T: [d 128][t 64] bf16 LINEAR (read direct to regs in main)
#pragma unroll
    for (int i = 0; i < 4; ++i) {
        const int u = tid + i * 256;   // d(128) x ch(8)
        const int d = u >> 3, ch = u & 7;
        float v[8];
#pragma unroll
        for (int k = 0; k < 8; ++k) v[k] = sVt[(8 * ch + k) * 128 + d];
        uint4 p;
        p.x = pk2(v[0], v[1]); p.y = pk2(v[2], v[3]);
        p.z = pk2(v[4], v[5]); p.w = pk2(v[6], v[7]);
        *(uint4*)(vout + d * 128 + 16 * ch) = p;
    }
}

// ---------------- main attention ----------------
#define GLL16(G, L) __builtin_amdgcn_global_load_lds(                         \
    (const uint_t __attribute__((address_space(1)))*)(G),                     \
    (uint_t __attribute__((address_space(3)))*)(L), 16, 0, 0)

// Stage K tile JB only: 4 glls/thread (16KB).
#define STAGE_K(JB, KB) {                                                     \
    const char* ks = kvbf + (size_t)(hkv * 16 + (JB)) * KSW_TILE              \
                   + w * 4096 + lane * 16;                                    \
    _Pragma("unroll")                                                         \
    for (int i = 0; i < 4; ++i)                                               \
        GLL16(ks + i * 1024, (KB) + w * 4096 + i * 1024);                     \
}

__launch_bounds__(256, 3)
__global__ void attn_main(const float* __restrict__ q,
                          const char* __restrict__ kvbf,
                          float* __restrict__ out,
                          char* __restrict__ wsb)
{
    __shared__ __align__(16) char sK[2][16384];
    __shared__ __align__(16) char sP[4][2048];

    const int bid = blockIdx.x;
    // bid<512: SPLIT halves of qt>=8 (long first). bid>=512: DIRECT qt<8.
    int qt, jb0, jb1, h, mode;         // mode 0 direct, 1 half0, 2 half1
    if (bid < 512) {
        const int half = bid & 1;
        const int idx  = bid >> 1;     // 0..255 carries (qt, h)
        qt  = 15 - (idx >> 5);         // 15..8
        h   = idx & 31;
        const int nt  = qt + 1;
        const int nt0 = (nt + 1) >> 1;
        jb0 = half ? nt0 : 0;
        jb1 = half ? nt : nt0;
        mode = half ? 2 : 1;
    } else {
        const int didx = bid - 512;
        qt  = 7 - (didx >> 5);         // 7..0 (long first)
        h   = didx & 31;
        jb0 = 0; jb1 = qt + 1;
        mode = 0;
    }
    const int hkv = h >> 2;
    const int tid  = threadIdx.x;
    const int w    = tid >> 6;
    const int lane = tid & 63;
    const int l15  = lane & 15;
    const int lhi  = lane >> 4;
    const int rg   = w;                // 16-row group

    // ---- Q fragments (SCALE folded): wave rows qt*64 + rg*16 + l15
    short8 qf[4];
    {
        const int qrow = qt * 64 + rg * 16 + l15;
        const float* qp = q + (size_t)qrow * Q_STRIDE + h * 128;
#pragma unroll
        for (int s = 0; s < 4; ++s) {
            const int d0 = s * 32 + lhi * 8;
            float4 a = *(const float4*)(qp + d0);
            float4 b = *(const float4*)(qp + d0 + 4);
            short8 v;
            v[0] = (short)f2bf(a.x * SCALE); v[1] = (short)f2bf(a.y * SCALE);
            v[2] = (short)f2bf(a.z * SCALE); v[3] = (short)f2bf(a.w * SCALE);
            v[4] = (short)f2bf(b.x * SCALE); v[5] = (short)f2bf(b.y * SCALE);
            v[6] = (short)f2bf(b.z * SCALE); v[7] = (short)f2bf(b.w * SCALE);
            qf[s] = v;
        }
    }

    f32x4 acc[8];
#pragma unroll
    for (int n2 = 0; n2 < 8; ++n2) acc[n2] = (f32x4){0.f, 0.f, 0.f, 0.f};
    float m_run[4]  = {-1e30f, -1e30f, -1e30f, -1e30f};
    float l_part[4] = {0.f, 0.f, 0.f, 0.f};

    STAGE_K(jb0, sK[0])
    __syncthreads();

    char* pb = sP[w];
    for (int jb = jb0; jb < jb1; ++jb) {
        const int cur = (jb - jb0) & 1;
        char* kbuf = sK[cur];
        const bool pf = (jb + 1 < jb1);
        if (pf) {
            STAGE_K(jb + 1, sK[cur ^ 1])
        }

        // ---- S = Q K^T
        f32x4 sacc[4];
#pragma unroll
        for (int n = 0; n < 4; ++n) sacc[n] = (f32x4){0.f, 0.f, 0.f, 0.f};
#pragma unroll
        for (int s = 0; s < 4; ++s) {
#pragma unroll
            for (int n = 0; n < 4; ++n) {
                const int tok = n * 16 + l15;
                const uint_t byte = (uint_t)(tok * 256)
                    + (((uint_t)((s * 32 + lhi * 8) * 2)) ^ ((uint_t)((tok & 7) << 4)));
                short8 kb = *(const short8*)(kbuf + byte);
                sacc[n] = __builtin_amdgcn_mfma_f32_16x16x32_bf16(qf[s], kb, sacc[n], 0, 0, 0);
            }
        }

        // ---- V^T fragments (s2=0) direct from L2; land during softmax
        const char* vt = kvbf + VSW_OFF + (size_t)(hkv * 16 + jb) * KSW_TILE;
        short8 vb0[8];
#pragma unroll
        for (int n2 = 0; n2 < 8; ++n2)
            vb0[n2] = *(const short8*)(vt + (n2 * 16 + l15) * 128 + lhi * 16);

        // ---- softmax with deferred max, in place
        const bool diag = (jb == qt);
        if (diag) {
#pragma unroll
            for (int n = 0; n < 4; ++n)
#pragma unroll
                for (int j = 0; j < 4; ++j) {
                    const int tok = jb * 64 + n * 16 + l15;
                    const int qg  = qt * 64 + rg * 16 + lhi * 4 + j;
                    if (tok > qg) sacc[n][j] = -1e30f;
                }
        }
#pragma unroll
        for (int j = 0; j < 4; ++j) {
            float lmax = fmaxf(fmaxf(sacc[0][j], sacc[1][j]),
                               fmaxf(sacc[2][j], sacc[3][j]));
            if (__any(lmax > m_run[j] + RESCALE_THR)) {
                float mt = lmax;
#pragma unroll
                for (int off = 1; off < 16; off <<= 1)
                    mt = fmaxf(mt, __shfl_xor(mt, off));
                const float mn = fmaxf(m_run[j], mt);
                const float alpha = __expf(m_run[j] - mn);
                m_run[j] = mn;
                l_part[j] *= alpha;
#pragma unroll
                for (int n2 = 0; n2 < 8; ++n2) acc[n2][j] *= alpha;
            }
            float ls = 0.f;
#pragma unroll
            for (int n = 0; n < 4; ++n) {
                float p = __expf(sacc[n][j] - m_run[j]);
                sacc[n][j] = p;
                ls += p;
            }
            l_part[j] += ls;
        }

        // ---- V^T fragments (s2=1); land during P write + PV pass 0
        short8 vb1[8];
#pragma unroll
        for (int n2 = 0; n2 < 8; ++n2)
            vb1[n2] = *(const short8*)(vt + (n2 * 16 + l15) * 128 + 64 + lhi * 16);

        // ---- P -> per-wave LDS (A-fragment relayout); same-wave lgkmcnt
#pragma unroll
        for (int n = 0; n < 4; ++n)
#pragma unroll
            for (int j = 0; j < 4; ++j) {
                const int r = lhi * 4 + j;
                const uint_t byte = (uint_t)(r * 128)
                    + (((uint_t)((n * 16 + l15) * 2)) ^ ((uint_t)((r & 7) << 4)));
                *(ushort_t*)(pb + byte) = f2bf(sacc[n][j]);
            }

        // ---- O += P V (V from registers)
        {
            const uint_t pbyte0 = (uint_t)(l15 * 128)
                + (((uint_t)((lhi * 8) * 2)) ^ ((uint_t)((l15 & 7) << 4)));
            short8 pa0 = *(const short8*)(pb + pbyte0);
#pragma unroll
            for (int n2 = 0; n2 < 8; ++n2)
                acc[n2] = __builtin_amdgcn_mfma_f32_16x16x32_bf16(pa0, vb0[n2], acc[n2], 0, 0, 0);
            const uint_t pbyte1 = (uint_t)(l15 * 128)
                + (((uint_t)((32 + lhi * 8) * 2)) ^ ((uint_t)((l15 & 7) << 4)));
            short8 pa1 = *(const short8*)(pb + pbyte1);
#pragma unroll
            for (int n2 = 0; n2 < 8; ++n2)
                acc[n2] = __builtin_amdgcn_mfma_f32_16x16x32_bf16(pa1, vb1[n2], acc[n2], 0, 0, 0);
        }

        if (pf) __syncthreads();   // drains K gll + guards buffer overwrite
    }

    // ---- epilogue
#pragma unroll
    for (int j = 0; j < 4; ++j) {
        float lsum = l_part[j];
#pragma unroll
        for (int off = 1; off < 16; off <<= 1)
            lsum += __shfl_xor(lsum, off);
        const int row64 = rg * 16 + lhi * 4 + j;
        const int qg    = qt * 64 + row64;
        if (mode == 0) {
            const float inv = 1.0f / lsum;
            float* dst = out + (size_t)qg * Q_STRIDE + h * 128;
#pragma unroll
            for (int n2 = 0; n2 < 8; ++n2)
                dst[n2 * 16 + l15] = acc[n2][j] * inv;
        } else {
            const int idx = (qt * 32 + h) * 64 + row64;
            if (mode == 1) {
                float* dst = out + (size_t)qg * Q_STRIDE + h * 128;
#pragma unroll
                for (int n2 = 0; n2 < 8; ++n2)
                    dst[n2 * 16 + l15] = acc[n2][j];   // unnormalized
                if (l15 == 0) {
                    float* ml = (float*)(wsb + ML0_OFF) + (size_t)idx * 2;
                    ml[0] = m_run[j]; ml[1] = lsum;
                }
            } else {
                ushort_t* dst = (ushort_t*)(wsb + ACC1_OFF) + (size_t)idx * 128;
#pragma unroll
                for (int n2 = 0; n2 < 8; ++n2)
                    dst[n2 * 16 + l15] = f2bf(acc[n2][j]);
                if (l15 == 0) {
                    float* ml = (float*)(wsb + ML1_OFF) + (size_t)idx * 2;
                    ml[0] = m_run[j]; ml[1] = lsum;
                }
            }
        }
    }
}

// ---------------- combine (qt>=8 rows only) ----------------
__launch_bounds__(256)
__global__ void attn_combine(float* __restrict__ out, const char* __restrict__ wsb)
{
    const int pid = blockIdx.x;           // 256 = (qt-8)(8) x h(32)
    const int qt = 8 + (pid >> 5);
    const int h  = pid & 31;
    const int tid = threadIdx.x;
    const int d4  = (tid & 31) * 4;
    const float* ml0b = (const float*)(wsb + ML0_OFF);
    const float* ml1b = (const float*)(wsb + ML1_OFF);
    const ushort_t* a1b = (const ushort_t*)(wsb + ACC1_OFF);

#pragma unroll
    for (int p = 0; p < 8; ++p) {
        const int r = (tid >> 5) + p * 8;            // row 0..63
        const size_t idx = (size_t)(qt * 32 + h) * 64 + r;
        const float m1 = ml0b[idx * 2], l1 = ml0b[idx * 2 + 1];
        const float m2 = ml1b[idx * 2], l2 = ml1b[idx * 2 + 1];
        const float m  = fmaxf(m1, m2);
        const float a1 = __expf(m1 - m), a2 = __expf(m2 - m);
        const float inv = 1.0f / (l1 * a1 + l2 * a2);
        float* o = out + (size_t)(qt * 64 + r) * Q_STRIDE + h * 128 + d4;
        const ushort_t* y4 = a1b + idx * 128 + d4;
        float4 x = *(const float4*)o;
        x.x = (x.x * a1 + bf2f(y4[0]) * a2) * inv;
        x.y = (x.y * a1 + bf2f(y4[1]) * a2) * inv;
        x.z = (x.z * a1 + bf2f(y4[2]) * a2) * inv;
        x.w = (x.w * a1 + bf2f(y4[3]) * a2) * inv;
        *(float4*)o = x;
    }
}

extern "C" void kernel_launch(void* const* d_in, const int* in_sizes, int n_in,
                              void* d_out, int out_size, void* d_ws, size_t ws_size,
                              hipStream_t stream) {
    const float* q   = (const float*)d_in[0];
    // d_in[1] (k) and d_in[2] (v) are dead under the reference's causal mask.
    const float* kvc = (const float*)d_in[3];
    const int*   bt  = (const int*)d_in[4];
    float* out = (float*)d_out;
    char*  wsb = (char*)d_ws;
    prep_kv<<<dim3(128), dim3(256), 0, stream>>>(kvc, bt, wsb);
    attn_main<<<dim3(768), dim3(256), 0, stream>>>(q, wsb, out, wsb);
    attn_combine<<<dim3(256), dim3(256), 0, stream>>>(out, wsb);
}

// Round 17
// 46.279 us; speedup vs baseline: 1.9508x; 1.4181x over previous
//
#include <hip/hip_runtime.h>
#include <hip/hip_bf16.h>

// GQA paged-prefill attention, MI355X gfx950.
// Causal mask j<=i over concat(past,new) => only first Q_LEN (=1024) gathered
// past tokens are live. Flash-attention over tokens 0..1023 of paged cache.
//
// R17: 4 INDEPENDENT blocks/CU (4 wave-streams/SIMD) with the proven R6
// per-tile chain. LDS 40KB: single-buffered K/V in LDS, double-buffered
// through REGISTERS (load next tile to named float4 regs before compute,
// ds_write after compute between two barriers). exp2-domain softmax
// (log2e folded into SCALE). setprio(1) around MFMA clusters.

#define Q_STRIDE 4096
// SCALE * log2(e): softmax computed in exp2 domain (v_exp_f32 is exp2).
#define SCALE2 0.1275179114285314f
#define RESCALE_THR 8.0f
#define KSW_TILE 16384                 // bytes per (hkv, jb) tile
#define VSW_OFF (2 * 1024 * 1024)      // Vt tiles start 2MB into ws

typedef short short8 __attribute__((ext_vector_type(8)));
typedef float f32x4 __attribute__((ext_vector_type(4)));
typedef unsigned short ushort_t;
typedef unsigned int uint_t;

__device__ __forceinline__ ushort_t f2bf(float f) {
    return __builtin_bit_cast(ushort_t, __float2bfloat16(f));
}
__device__ __forceinline__ uint_t pk2(float a, float b) {
    return (uint_t)f2bf(a) | ((uint_t)f2bf(b) << 16);
}

// ---------------- prep: paged fp32 -> dense swizzled bf16 ----------------
__launch_bounds__(256)
__global__ void prep_kv(const float* __restrict__ kvc,
                        const int* __restrict__ bt,
                        char* __restrict__ wsb)
{
    __shared__ float sVt[64 * 128];
    const int blk = blockIdx.x;        // 128 blocks = hkv(8) x jb(16)
    const int hkv = blk >> 4;
    const int jb  = blk & 15;
    const int tid = threadIdx.x;
    char* kout = wsb + (size_t)(hkv * 16 + jb) * KSW_TILE;
    char* vout = wsb + VSW_OFF + (size_t)(hkv * 16 + jb) * KSW_TILE;

    // K: [t 64][d 128] bf16, 16B chunk c at byte t*256 + ((c*16)^((t&7)<<4))
#pragma unroll
    for (int i = 0; i < 4; ++i) {
        const int u = tid + i * 256;   // t(64) x c(16)
        const int t = u >> 4, c = u & 15;
        const int gtok = jb * 64 + t;
        const int page = bt[gtok >> 4];
        const float* src = kvc + (size_t)page * 32768 + (size_t)hkv * 2048
                         + (gtok & 15) * 128 + c * 8;
        float4 a = *(const float4*)src;
        float4 b = *(const float4*)(src + 4);
        uint4 p;
        p.x = pk2(a.x, a.y); p.y = pk2(a.z, a.w);
        p.z = pk2(b.x, b.y); p.w = pk2(b.z, b.w);
        *(uint4*)(kout + t * 256 + ((c * 16) ^ ((t & 7) << 4))) = p;
    }
    // V: coalesced fp32 read -> LDS ([t][d])
#pragma unroll
    for (int i = 0; i < 8; ++i) {
        const int u = tid + i * 256;   // t(64) x c4(32)
        const int t = u >> 5, c4 = u & 31;
        const int gtok = jb * 64 + t;
        const int page = bt[gtok >> 4];
        const float* src = kvc + (size_t)page * 32768 + 16384
                         + (size_t)hkv * 2048 + (gtok & 15) * 128 + c4 * 4;
        *(float4*)(sVt + t * 128 + c4 * 4) = *(const float4*)src;
    }
    __syncthreads();
    // Vt: [d 128][t 64] bf16, 16B chunk ch at byte (d*128+16*ch)^((d&7)<<4)
#pragma unroll
    for (int i = 0; i < 4; ++i) {
        const int u = tid + i * 256;   // d(128) x ch(8)
        const int d = u >> 3, ch = u & 7;
        float v[8];
#pragma unroll
        for (int k = 0; k < 8; ++k) v[k] = sVt[(8 * ch + k) * 128 + d];
        uint4 p;
        p.x = pk2(v[0], v[1]); p.y = pk2(v[2], v[3]);
        p.z = pk2(v[4], v[5]); p.w = pk2(v[6], v[7]);
        *(uint4*)(vout + ((d * 128 + 16 * ch) ^ ((d & 7) << 4))) = p;
    }
}

// ---------------- main attention ----------------
#define GLL16(G, L) __builtin_amdgcn_global_load_lds(                         \
    (const uint_t __attribute__((address_space(1)))*)(G),                     \
    (uint_t __attribute__((address_space(3)))*)(L), 16, 0, 0)

__launch_bounds__(256)
__global__ void attn_main(const float* __restrict__ q,
                          const char* __restrict__ kvbf,
                          float* __restrict__ out)
{
    __shared__ __align__(16) char sK[16384];
    __shared__ __align__(16) char sV[16384];
    __shared__ __align__(16) char sP[4][2048];   // 40KB total -> 4 blocks/CU

    const int bid = blockIdx.x;
    const int h   = bid & 31;
    const int qt  = 15 - (bid >> 5);   // long blocks first
    const int hkv = h >> 2;
    const int tid  = threadIdx.x;
    const int w    = tid >> 6;
    const int lane = tid & 63;
    const int l15  = lane & 15;
    const int lhi  = lane >> 4;

    // ---- Q fragments (SCALE2 folded -> exp2 domain)
    short8 qf[4];
    {
        const int qrow = qt * 64 + w * 16 + l15;
        const float* qp = q + (size_t)qrow * Q_STRIDE + h * 128;
#pragma unroll
        for (int s = 0; s < 4; ++s) {
            const int d0 = s * 32 + lhi * 8;
            float4 a = *(const float4*)(qp + d0);
            float4 b = *(const float4*)(qp + d0 + 4);
            short8 v;
            v[0] = (short)f2bf(a.x * SCALE2); v[1] = (short)f2bf(a.y * SCALE2);
            v[2] = (short)f2bf(a.z * SCALE2); v[3] = (short)f2bf(a.w * SCALE2);
            v[4] = (short)f2bf(b.x * SCALE2); v[5] = (short)f2bf(b.y * SCALE2);
            v[6] = (short)f2bf(b.z * SCALE2); v[7] = (short)f2bf(b.w * SCALE2);
            qf[s] = v;
        }
    }

    f32x4 acc[8];
#pragma unroll
    for (int n2 = 0; n2 < 8; ++n2) acc[n2] = (f32x4){0.f, 0.f, 0.f, 0.f};
    float m_run[4]  = {-1e30f, -1e30f, -1e30f, -1e30f};
    float l_part[4] = {0.f, 0.f, 0.f, 0.f};

    // prologue: tile 0 -> LDS via DMA, one full drain
    {
        const char* b0 = kvbf + (size_t)(hkv * 16) * KSW_TILE + w * 4096 + lane * 16;
#pragma unroll
        for (int i = 0; i < 4; ++i) {
            GLL16(b0 + i * 1024,           sK + w * 4096 + i * 1024);
            GLL16(b0 + VSW_OFF + i * 1024, sV + w * 4096 + i * 1024);
        }
    }
    __syncthreads();

    char* pb = sP[w];
    for (int jb = 0; jb <= qt; ++jb) {
        const bool pf = (jb < qt);

        // ---- issue next tile's loads to NAMED registers (land under compute)
        float4 kr0, kr1, kr2, kr3, vr0, vr1, vr2, vr3;
        if (pf) {
            const char* nb = kvbf + (size_t)(hkv * 16 + jb + 1) * KSW_TILE
                           + w * 4096 + lane * 16;
            kr0 = *(const float4*)(nb);
            kr1 = *(const float4*)(nb + 1024);
            kr2 = *(const float4*)(nb + 2048);
            kr3 = *(const float4*)(nb + 3072);
            const char* nv = nb + VSW_OFF;
            vr0 = *(const float4*)(nv);
            vr1 = *(const float4*)(nv + 1024);
            vr2 = *(const float4*)(nv + 2048);
            vr3 = *(const float4*)(nv + 3072);
        }

        // ---- S = Q K^T
        f32x4 sacc[4];
#pragma unroll
        for (int n = 0; n < 4; ++n) sacc[n] = (f32x4){0.f, 0.f, 0.f, 0.f};
        __builtin_amdgcn_s_setprio(1);
#pragma unroll
        for (int s = 0; s < 4; ++s) {
#pragma unroll
            for (int n = 0; n < 4; ++n) {
                const int tok = n * 16 + l15;
                const uint_t byte = (uint_t)(tok * 256)
                    + (((uint_t)((s * 32 + lhi * 8) * 2)) ^ ((uint_t)((tok & 7) << 4)));
                short8 kb = *(const short8*)(sK + byte);
                sacc[n] = __builtin_amdgcn_mfma_f32_16x16x32_bf16(qf[s], kb, sacc[n], 0, 0, 0);
            }
        }
        __builtin_amdgcn_s_setprio(0);

        // ---- softmax (exp2 domain) with deferred max
        const bool diag = (jb == qt);
        if (diag) {
#pragma unroll
            for (int n = 0; n < 4; ++n)
#pragma unroll
                for (int j = 0; j < 4; ++j) {
                    const int tok = jb * 64 + n * 16 + l15;
                    const int qg  = qt * 64 + w * 16 + lhi * 4 + j;
                    if (tok > qg) sacc[n][j] = -1e30f;
                }
        }
#pragma unroll
        for (int j = 0; j < 4; ++j) {
            float lmax = fmaxf(fmaxf(sacc[0][j], sacc[1][j]),
                               fmaxf(sacc[2][j], sacc[3][j]));
            if (__any(lmax > m_run[j] + RESCALE_THR)) {
                float mt = lmax;
#pragma unroll
                for (int off = 1; off < 16; off <<= 1)
                    mt = fmaxf(mt, __shfl_xor(mt, off));
                const float mn = fmaxf(m_run[j], mt);
                const float alpha = exp2f(m_run[j] - mn);
                m_run[j] = mn;
                l_part[j] *= alpha;
#pragma unroll
                for (int n2 = 0; n2 < 8; ++n2) acc[n2][j] *= alpha;
            }
            float ls = 0.f;
#pragma unroll
            for (int n = 0; n < 4; ++n) {
                float p = exp2f(sacc[n][j] - m_run[j]);
                sacc[n][j] = p;
                ls += p;
            }
            l_part[j] += ls;
        }

        // ---- P -> per-wave LDS (A-fragment relayout); same-wave lgkmcnt
#pragma unroll
        for (int n = 0; n < 4; ++n)
#pragma unroll
            for (int j = 0; j < 4; ++j) {
                const int r = lhi * 4 + j;
                const uint_t byte = (uint_t)(r * 128)
                    + (((uint_t)((n * 16 + l15) * 2)) ^ ((uint_t)((r & 7) << 4)));
                *(ushort_t*)(pb + byte) = f2bf(sacc[n][j]);
            }

        // ---- O += P V
        __builtin_amdgcn_s_setprio(1);
#pragma unroll
        for (int s2 = 0; s2 < 2; ++s2) {
            const uint_t pbyte = (uint_t)(l15 * 128)
                + (((uint_t)((s2 * 32 + lhi * 8) * 2)) ^ ((uint_t)((l15 & 7) << 4)));
            short8 pa = *(const short8*)(pb + pbyte);
#pragma unroll
            for (int n2 = 0; n2 < 8; ++n2) {
                const int dim = n2 * 16 + l15;
                const uint_t vbyte = (uint_t)(dim * 128)
                    + (((uint_t)((s2 * 32 + lhi * 8) * 2)) ^ ((uint_t)((dim & 7) << 4)));
                short8 vbf = *(const short8*)(sV + vbyte);
                acc[n2] = __builtin_amdgcn_mfma_f32_16x16x32_bf16(pa, vbf, acc[n2], 0, 0, 0);
            }
        }
        __builtin_amdgcn_s_setprio(0);

        if (pf) {
            __syncthreads();   // all waves done reading sK/sV for tile jb
            // write prefetched tile jb+1 (vmcnt wait hidden under compute)
            *(float4*)(sK + w * 4096 + lane * 16)        = kr0;
            *(float4*)(sK + w * 4096 + 1024 + lane * 16) = kr1;
            *(float4*)(sK + w * 4096 + 2048 + lane * 16) = kr2;
            *(float4*)(sK + w * 4096 + 3072 + lane * 16) = kr3;
            *(float4*)(sV + w * 4096 + lane * 16)        = vr0;
            *(float4*)(sV + w * 4096 + 1024 + lane * 16) = vr1;
            *(float4*)(sV + w * 4096 + 2048 + lane * 16) = vr2;
            *(float4*)(sV + w * 4096 + 3072 + lane * 16) = vr3;
            __syncthreads();   // tile jb+1 visible to all
        }
    }

    // ---- epilogue: reduce per-lane l across 16-lane row group, store
#pragma unroll
    for (int j = 0; j < 4; ++j) {
        float lsum = l_part[j];
#pragma unroll
        for (int off = 1; off < 16; off <<= 1)
            lsum += __shfl_xor(lsum, off);
        const float inv = 1.0f / lsum;
        const int qg = qt * 64 + w * 16 + lhi * 4 + j;
        float* dst = out + (size_t)qg * Q_STRIDE + h * 128;
#pragma unroll
        for (int n2 = 0; n2 < 8; ++n2)
            dst[n2 * 16 + l15] = acc[n2][j] * inv;
    }
}

extern "C" void kernel_launch(void* const* d_in, const int* in_sizes, int n_in,
                              void* d_out, int out_size, void* d_ws, size_t ws_size,
                              hipStream_t stream) {
    const float* q   = (const float*)d_in[0];
    // d_in[1] (k) and d_in[2] (v) are dead under the reference's causal mask.
    const float* kvc = (const float*)d_in[3];
    const int*   bt  = (const int*)d_in[4];
    float* out = (float*)d_out;
    char*  wsb = (char*)d_ws;
    prep_kv<<<dim3(128), dim3(256), 0, stream>>>(kvc, bt, wsb);
    attn_main<<<dim3(512), dim3(256), 0, stream>>>(q, wsb, out);
}